// Round 1
// baseline (230.798 us; speedup 1.0000x reference)
//
#include <hip/hip_runtime.h>

// LIF spike scan: x[N, T=32] fp32, scan over contiguous T axis.
//   u = 0.25*u*(1-o_prev) + x_t ;  o = (u > 0.5) ? 1 : 0
// 0.25*u exact (pow2), (1-o) in {0,1} exact -> bit-exact vs numpy fp32 ref.
//
// R3: barrier-free wave-private transpose.
//  - Each wave owns a private 512-float4 (8 KB) LDS region: 64 neurons x 32 T.
//    No __syncthreads() anywhere -> no block-wide vmcnt(0)+s_barrier drains;
//    every wave on the CU makes independent forward progress.
//  - Phase 1 uses global_load_lds (async HBM->LDS, 16B/lane). The async path
//    writes LDS linearly (wave-uniform base + lane*16), so the bank-conflict
//    XOR swizzle is applied to the GLOBAL source address instead (involution;
//    it permutes float4s only within each 128B cache line, so the loads stay
//    fully coalesced) and re-applied on the phase-3 LDS read.
//  - Per-wave s_waitcnt vmcnt(0) replaces the first barrier; DS in-order
//    execution per wave replaces the second (lgkmcnt(0) pins compiler order).

constexpr int T = 32;
constexpr float TAU = 0.25f;
constexpr float VTH = 0.5f;
constexpr int QPR = T / 4;                       // 8 float4 per neuron row
constexpr int WAVE_F4 = 64 * QPR;                // 512 float4 per wave (8 KB)
constexpr int BLOCK = 256;
constexpr int TILE_F4 = (BLOCK / 64) * WAVE_F4;  // 2048 float4 per block (32 KB)

__device__ __forceinline__ int swz(int s) { return s ^ ((s >> 3) & 7); }

__global__ __launch_bounds__(256) void LIFSpike_kernel(
    const float* __restrict__ x, float* __restrict__ out) {
    __shared__ float4 tile[TILE_F4];  // 32 KB, wave w owns [w*512, w*512+512)

    const int t = threadIdx.x;
    const int lane = t & 63;
    const int wid = t >> 6;
    const int wbase = wid * WAVE_F4;
    const size_t base = (size_t)blockIdx.x * TILE_F4;  // in float4 units

    const float4* __restrict__ xp = reinterpret_cast<const float4*>(x);
    float4* __restrict__ op = reinterpret_cast<float4*>(out);

    // Phase 1: async global -> LDS, 8 x 1KB per wave. LDS dest is linear
    // (wave-uniform base; HW adds lane*16). Global source is pre-swizzled so
    // that tile[p] = xp[base + swz(p)]  (swz is an involution).
#pragma unroll
    for (int k = 0; k < QPR; ++k) {
        const int p = wbase + k * 64;       // wave-uniform LDS f4 base
        const int src = swz(p + lane);      // per-lane swizzled source index
        __builtin_amdgcn_global_load_lds(
            (const __attribute__((address_space(1))) void*)(xp + base + src),
            (__attribute__((address_space(3))) void*)(tile + p),
            16, 0, 0);
    }
    // Wait for this wave's own async loads only -- no block barrier.
    asm volatile("s_waitcnt vmcnt(0)" ::: "memory");

    // Phase 2: each thread scans its own 32-step row (thread-private
    // addresses inside the wave's region; in-place writeback).
    float u = 0.0f, o = 0.0f;
#pragma unroll
    for (int j = 0; j < QPR; ++j) {
        const int phys = t * QPR + (j ^ (t & 7));  // == swz(t*8 + j)
        float4 v = tile[phys];
        float4 r;

        u = TAU * u * (1.0f - o) + v.x;
        o = (u > VTH) ? 1.0f : 0.0f;
        r.x = o;

        u = TAU * u * (1.0f - o) + v.y;
        o = (u > VTH) ? 1.0f : 0.0f;
        r.y = o;

        u = TAU * u * (1.0f - o) + v.z;
        o = (u > VTH) ? 1.0f : 0.0f;
        r.z = o;

        u = TAU * u * (1.0f - o) + v.w;
        o = (u > VTH) ? 1.0f : 0.0f;
        r.w = o;

        tile[phys] = r;
    }
    // Cross-lane handoff within the wave: DS ops are in-order per wave;
    // the explicit lgkmcnt(0) + memory clobber pins compiler ordering.
    asm volatile("s_waitcnt lgkmcnt(0)" ::: "memory");

    // Phase 3: coalesced LDS -> global (linear store, swizzled LDS read).
#pragma unroll
    for (int k = 0; k < QPR; ++k) {
        const int p = wbase + k * 64 + lane;
        op[base + p] = tile[swz(p)];
    }
}

extern "C" void kernel_launch(void* const* d_in, const int* in_sizes, int n_in,
                              void* d_out, int out_size, void* d_ws, size_t ws_size,
                              hipStream_t stream) {
    const float* x = (const float*)d_in[0];
    float* out = (float*)d_out;
    int total_f4 = in_sizes[0] / 4;       // 8,388,608
    int grid = total_f4 / TILE_F4;        // 4096 blocks (exact)
    LIFSpike_kernel<<<grid, BLOCK, 0, stream>>>(x, out);
}